// Round 1
// baseline (476.658 us; speedup 1.0000x reference)
//
#include <hip/hip_runtime.h>

#define EMBED 512
#define LATENT 32
#define SEQ 2048
#define MTOT 4096
#define VOCAB 32000

typedef float f32x4 __attribute__((ext_vector_type(4)));
typedef short s16x8 __attribute__((ext_vector_type(8)));

__device__ __forceinline__ unsigned short f2bf(float f) {
  unsigned u = __float_as_uint(f);
  u += 0x7FFFu + ((u >> 16) & 1u);
  return (unsigned short)(u >> 16);
}

// ---------------- downscale: lat = in @ Wd + bd (4 streams) -----------------
__global__ __launch_bounds__(128) void k_downscale(
    const float* __restrict__ Q, const float* __restrict__ K,
    const float* __restrict__ V, const float* __restrict__ X,
    const float* __restrict__ Wd, const float* __restrict__ bd,
    float* __restrict__ latq, float* __restrict__ latk,
    float* __restrict__ latv, float* __restrict__ latx) {
  const float* in; float* out;
  switch (blockIdx.y) {
    case 0: in = Q; out = latq; break;
    case 1: in = K; out = latk; break;
    case 2: in = V; out = latv; break;
    default: in = X; out = latx; break;
  }
  int r = blockIdx.x;
  int t = threadIdx.x;
  int col = t & 31, part = t >> 5;
  const float* rowp = in + (size_t)r * EMBED + part * 128;
  const float* wd = Wd + col;
  float acc = 0.f;
#pragma unroll 8
  for (int kk = 0; kk < 128; kk += 4) {
    f32x4 iv = *(const f32x4*)(rowp + kk);
    int k = part * 128 + kk;
    acc += iv.x * wd[(k + 0) * 32];
    acc += iv.y * wd[(k + 1) * 32];
    acc += iv.z * wd[(k + 2) * 32];
    acc += iv.w * wd[(k + 3) * 32];
  }
  __shared__ float red[4][32];
  red[part][col] = acc;
  __syncthreads();
  if (t < 32) {
    out[(size_t)r * 32 + t] =
        red[0][t] + red[1][t] + red[2][t] + red[3][t] + bd[t];
  }
}

// ---------------- causal attention over latent dim 32 -----------------
// One wave per query row; lanes parallel over keys; per-lane online softmax,
// cross-lane merge at the end. Blocks balanced: wave w of block b handles
// queries {b, 2047-b, 2048+b, 4095-b} (work sum constant per block).
__global__ __launch_bounds__(256) void k_attn(
    const float* __restrict__ lq, const float* __restrict__ lk,
    const float* __restrict__ lv, float* __restrict__ ctx) {
  int lane = threadIdx.x & 63;
  int lw = threadIdx.x >> 6;
  int bl = blockIdx.x;  // 0..1023
  int qg;
  switch (lw) {
    case 0: qg = bl; break;
    case 1: qg = 2047 - bl; break;
    case 2: qg = 2048 + bl; break;
    default: qg = 4095 - bl; break;
  }
  int batch = qg >> 11;
  int qi = qg & 2047;
  const float* qp = lq + (size_t)qg * 32;
  f32x4 q4[8], ca[8];
#pragma unroll
  for (int d = 0; d < 8; ++d) {
    q4[d] = *(const f32x4*)(qp + d * 4);
    ca[d] = f32x4{0.f, 0.f, 0.f, 0.f};
  }
  const float* kb = lk + (size_t)batch * SEQ * 32;
  const float* vb = lv + (size_t)batch * SEQ * 32;
  float m = -INFINITY, ssum = 0.f;
  const float scale = 0.17677669529663687f;  // 1/sqrt(32)
  for (int j0 = 0; j0 <= qi; j0 += 64) {
    int j = j0 + lane;
    if (j <= qi) {
      const f32x4* kp = (const f32x4*)(kb + (size_t)j * 32);
      f32x4 s4 = f32x4{0.f, 0.f, 0.f, 0.f};
#pragma unroll
      for (int d = 0; d < 8; ++d) s4 += q4[d] * kp[d];
      float s = (s4.x + s4.y + s4.z + s4.w) * scale;
      float mn = fmaxf(m, s);
      float f = __expf(m - mn);  // expf(-inf)=0 on first valid key
      float p = __expf(s - mn);
      ssum = ssum * f + p;
      const f32x4* vp = (const f32x4*)(vb + (size_t)j * 32);
#pragma unroll
      for (int d = 0; d < 8; ++d) ca[d] = ca[d] * f + p * vp[d];
      m = mn;
    }
  }
  // cross-lane merge
  float M = m;
#pragma unroll
  for (int off = 32; off > 0; off >>= 1) M = fmaxf(M, __shfl_xor(M, off, 64));
  float sc = (m == -INFINITY) ? 0.f : __expf(m - M);
  ssum *= sc;
#pragma unroll
  for (int off = 32; off > 0; off >>= 1) ssum += __shfl_xor(ssum, off, 64);
#pragma unroll
  for (int d = 0; d < 8; ++d) {
    ca[d] *= sc;
#pragma unroll
    for (int off = 32; off > 0; off >>= 1) {
      ca[d].x += __shfl_xor(ca[d].x, off, 64);
      ca[d].y += __shfl_xor(ca[d].y, off, 64);
      ca[d].z += __shfl_xor(ca[d].z, off, 64);
      ca[d].w += __shfl_xor(ca[d].w, off, 64);
    }
  }
  float inv = 1.f / ssum;
  float outv = 0.f;
#pragma unroll
  for (int d = 0; d < 32; ++d) {
    if (lane == d) outv = ca[d >> 2][d & 3];
  }
  if (lane < 32) ctx[(size_t)qg * 32 + lane] = outv * inv;
}

// -------- upscale + tile(ctx x16) + LayerNorm -> bf16 enc --------
__global__ __launch_bounds__(512) void k_upln(
    const float* __restrict__ ctx, const float* __restrict__ latx,
    const float* __restrict__ Wu, const float* __restrict__ bu,
    const float* __restrict__ gamma, const float* __restrict__ beta,
    unsigned short* __restrict__ encb) {
  int r = blockIdx.x;
  int c = threadIdx.x;  // 0..511
  float acc = bu[c] + ctx[(size_t)r * 32 + (c & 31)];
  const float* lx = latx + (size_t)r * 32;
#pragma unroll
  for (int k = 0; k < 32; ++k) acc += lx[k] * Wu[k * EMBED + c];
  int lane = threadIdx.x & 63, w = threadIdx.x >> 6;
  float s1 = acc, s2 = acc * acc;
#pragma unroll
  for (int off = 32; off > 0; off >>= 1) {
    s1 += __shfl_xor(s1, off, 64);
    s2 += __shfl_xor(s2, off, 64);
  }
  __shared__ float r1[8], r2[8];
  if (lane == 0) { r1[w] = s1; r2[w] = s2; }
  __syncthreads();
  float t1 = 0.f, t2 = 0.f;
#pragma unroll
  for (int i = 0; i < 8; ++i) { t1 += r1[i]; t2 += r2[i]; }
  float mu = t1 * (1.f / 512.f);
  float var = t2 * (1.f / 512.f) - mu * mu;
  float rstd = rsqrtf(var + 1e-5f);
  float o = (acc - mu) * rstd * gamma[c] + beta[c];
  encb[(size_t)r * EMBED + c] = f2bf(o);
}

// -------- transpose + cast Wf [512][32000] f32 -> WfT [32000][512] bf16 -----
__global__ __launch_bounds__(256) void k_transcast(
    const float* __restrict__ Wf, unsigned short* __restrict__ wfT) {
  __shared__ float tile[64][65];
  int n0 = blockIdx.x * 64;
  int k0 = blockIdx.y * 64;
  int t = threadIdx.x;
  int rr = t >> 4;         // 0..15
  int cq = (t & 15) << 2;  // 0..60
#pragma unroll
  for (int p = 0; p < 4; ++p) {
    int kr = p * 16 + rr;
    f32x4 v = *(const f32x4*)(Wf + (size_t)(k0 + kr) * VOCAB + n0 + cq);
    tile[kr][cq + 0] = v.x;
    tile[kr][cq + 1] = v.y;
    tile[kr][cq + 2] = v.z;
    tile[kr][cq + 3] = v.w;
  }
  __syncthreads();
#pragma unroll
  for (int p = 0; p < 4; ++p) {
    int nr = p * 16 + rr;
    ushort4 u;
    u.x = f2bf(tile[cq + 0][nr]);
    u.y = f2bf(tile[cq + 1][nr]);
    u.z = f2bf(tile[cq + 2][nr]);
    u.w = f2bf(tile[cq + 3][nr]);
    *(ushort4*)(wfT + (size_t)(n0 + nr) * EMBED + k0 + cq) = u;
  }
}

// -------- final GEMM: C[4096][32000] = encb @ WfT^T + bf  (bf16 MFMA) -------
// m97-class: 128x128 tile, BK=64, 4 waves (2x2), 16x16x32 MFMA, linear LDS
// dest + source-side XOR swizzle (kb ^= (row&7)<<4) for conflict-free
// ds_read_b128.
#define BM 128
#define BN 128

__device__ __forceinline__ void mfma16x16x32(f32x4& d, s16x8 a, s16x8 b) {
  asm("v_mfma_f32_16x16x32_bf16 %0, %1, %2, %0" : "+v"(d) : "v"(a), "v"(b));
}

__device__ __forceinline__ void gload16(const void* g, void* l) {
  __builtin_amdgcn_global_load_lds(
      (const __attribute__((address_space(1))) void*)g,
      (__attribute__((address_space(3))) void*)l, 16, 0, 0);
}

__global__ __launch_bounds__(256, 2) void k_gemm(
    const unsigned short* __restrict__ A,   // [4096][512] bf16
    const unsigned short* __restrict__ Bt,  // [32000][512] bf16
    const float* __restrict__ bias, float* __restrict__ C) {
  __shared__ unsigned short As[BM * 64];
  __shared__ unsigned short Bs[BN * 64];
  int t = threadIdx.x;
  int lane = t & 63, wave = t >> 6;
  int wm = wave >> 1, wn = wave & 1;
  int fr = lane & 15, fq = lane >> 4;
  int m0 = blockIdx.y * BM;
  int n0 = blockIdx.x * BN;
  int srow = t >> 3;         // 0..31 (row within 32-row staging chunk)
  int skb = (t & 7) << 4;    // byte col within 128B row
  f32x4 acc[4][4];
#pragma unroll
  for (int i = 0; i < 4; ++i)
#pragma unroll
    for (int j = 0; j < 4; ++j) acc[i][j] = f32x4{0.f, 0.f, 0.f, 0.f};

  const char* Abase = (const char*)(A + (size_t)m0 * EMBED);
  const char* Bbase = (const char*)(Bt + (size_t)n0 * EMBED);

  for (int k0 = 0; k0 < EMBED; k0 += 64) {
#pragma unroll
    for (int it = 0; it < 4; ++it) {
      int row = srow + it * 32;
      int kbs = skb ^ ((row & 7) << 4);  // pre-swizzled global source
      gload16(Abase + (size_t)row * 1024 + k0 * 2 + kbs,
              (char*)As + row * 128 + skb);
    }
#pragma unroll
    for (int it = 0; it < 4; ++it) {
      int row = srow + it * 32;
      int kbs = skb ^ ((row & 7) << 4);
      gload16(Bbase + (size_t)row * 1024 + k0 * 2 + kbs,
              (char*)Bs + row * 128 + skb);
    }
    __syncthreads();
#pragma unroll
    for (int kki = 0; kki < 2; ++kki) {
      int kbyte = (kki * 32 + fq * 8) * 2;
      s16x8 af[4], bfr[4];
#pragma unroll
      for (int mi = 0; mi < 4; ++mi) {
        int row = wm * 64 + mi * 16 + fr;
        af[mi] = *(const s16x8*)((const char*)As + row * 128 +
                                 (kbyte ^ ((row & 7) << 4)));
      }
#pragma unroll
      for (int ni = 0; ni < 4; ++ni) {
        int row = wn * 64 + ni * 16 + fr;
        bfr[ni] = *(const s16x8*)((const char*)Bs + row * 128 +
                                  (kbyte ^ ((row & 7) << 4)));
      }
#pragma unroll
      for (int mi = 0; mi < 4; ++mi)
#pragma unroll
        for (int ni = 0; ni < 4; ++ni) mfma16x16x32(acc[mi][ni], af[mi], bfr[ni]);
    }
    __syncthreads();
  }
  // epilogue: add bias, store f32. C/D layout: col=lane&15, row=(lane>>4)*4+reg
  float bv[4];
#pragma unroll
  for (int ni = 0; ni < 4; ++ni) bv[ni] = bias[n0 + wn * 64 + ni * 16 + fr];
#pragma unroll
  for (int mi = 0; mi < 4; ++mi) {
#pragma unroll
    for (int ni = 0; ni < 4; ++ni) {
      int col = n0 + wn * 64 + ni * 16 + fr;
#pragma unroll
      for (int rg = 0; rg < 4; ++rg) {
        int rowg = m0 + wm * 64 + mi * 16 + fq * 4 + rg;
        C[(size_t)rowg * VOCAB + col] = acc[mi][ni][rg] + bv[ni];
      }
    }
  }
}

extern "C" void kernel_launch(void* const* d_in, const int* in_sizes, int n_in,
                              void* d_out, int out_size, void* d_ws,
                              size_t ws_size, hipStream_t stream) {
  const float* Q = (const float*)d_in[0];
  const float* K = (const float*)d_in[1];
  const float* V = (const float*)d_in[2];
  const float* X = (const float*)d_in[3];
  const float* Wd = (const float*)d_in[4];
  const float* bd = (const float*)d_in[5];
  const float* Wu = (const float*)d_in[6];
  const float* bu = (const float*)d_in[7];
  const float* gamma = (const float*)d_in[8];
  const float* beta = (const float*)d_in[9];
  const float* Wf = (const float*)d_in[10];
  const float* bf = (const float*)d_in[11];
  float* out = (float*)d_out;
  char* ws = (char*)d_ws;
  // ws layout (bytes): needs ~39.3 MB total
  float* latq = (float*)(ws + 0);
  float* latk = (float*)(ws + (1u << 19));
  float* latv = (float*)(ws + (2u << 19));
  float* latx = (float*)(ws + 3u * (1u << 19));
  float* ctx = (float*)(ws + (1u << 21));
  unsigned short* encb = (unsigned short*)(ws + (1u << 21) + (1u << 19));
  unsigned short* wfT =
      (unsigned short*)(ws + (1u << 21) + (1u << 19) + (1u << 22));

  k_downscale<<<dim3(MTOT, 4), 128, 0, stream>>>(Q, K, V, X, Wd, bd, latq,
                                                 latk, latv, latx);
  k_transcast<<<dim3(VOCAB / 64, EMBED / 64), 256, 0, stream>>>(Wf, wfT);
  k_attn<<<1024, 256, 0, stream>>>(latq, latk, latv, ctx);
  k_upln<<<MTOT, 512, 0, stream>>>(ctx, latx, Wu, bu, gamma, beta, encb);
  k_gemm<<<dim3(VOCAB / BN, MTOT / BM), 256, 0, stream>>>(encb, wfT, bf, out);
}

// Round 2
// 430.186 us; speedup vs baseline: 1.1080x; 1.1080x over previous
//
#include <hip/hip_runtime.h>

#define EMBED 512
#define LATENT 32
#define SEQ 2048
#define MTOT 4096
#define VOCAB 32000

typedef float f32x4 __attribute__((ext_vector_type(4)));
typedef short s16x8 __attribute__((ext_vector_type(8)));

__device__ __forceinline__ unsigned short f2bf(float f) {
  unsigned u = __float_as_uint(f);
  u += 0x7FFFu + ((u >> 16) & 1u);
  return (unsigned short)(u >> 16);
}

// ---------------- downscale: lat = in @ Wd + bd (4 streams) -----------------
__global__ __launch_bounds__(128) void k_downscale(
    const float* __restrict__ Q, const float* __restrict__ K,
    const float* __restrict__ V, const float* __restrict__ X,
    const float* __restrict__ Wd, const float* __restrict__ bd,
    float* __restrict__ latq, float* __restrict__ latk,
    float* __restrict__ latv, float* __restrict__ latx) {
  const float* in; float* out;
  switch (blockIdx.y) {
    case 0: in = Q; out = latq; break;
    case 1: in = K; out = latk; break;
    case 2: in = V; out = latv; break;
    default: in = X; out = latx; break;
  }
  int r = blockIdx.x;
  int t = threadIdx.x;
  int col = t & 31, part = t >> 5;
  const float* rowp = in + (size_t)r * EMBED + part * 128;
  const float* wd = Wd + col;
  float acc = 0.f;
#pragma unroll 8
  for (int kk = 0; kk < 128; kk += 4) {
    f32x4 iv = *(const f32x4*)(rowp + kk);
    int k = part * 128 + kk;
    acc += iv.x * wd[(k + 0) * 32];
    acc += iv.y * wd[(k + 1) * 32];
    acc += iv.z * wd[(k + 2) * 32];
    acc += iv.w * wd[(k + 3) * 32];
  }
  __shared__ float red[4][32];
  red[part][col] = acc;
  __syncthreads();
  if (t < 32) {
    out[(size_t)r * 32 + t] =
        red[0][t] + red[1][t] + red[2][t] + red[3][t] + bd[t];
  }
}

// ---------------- causal attention over latent dim 32 -----------------
__global__ __launch_bounds__(256) void k_attn(
    const float* __restrict__ lq, const float* __restrict__ lk,
    const float* __restrict__ lv, float* __restrict__ ctx) {
  int lane = threadIdx.x & 63;
  int lw = threadIdx.x >> 6;
  int bl = blockIdx.x;  // 0..1023
  int qg;
  switch (lw) {
    case 0: qg = bl; break;
    case 1: qg = 2047 - bl; break;
    case 2: qg = 2048 + bl; break;
    default: qg = 4095 - bl; break;
  }
  int batch = qg >> 11;
  int qi = qg & 2047;
  const float* qp = lq + (size_t)qg * 32;
  f32x4 q4[8], ca[8];
#pragma unroll
  for (int d = 0; d < 8; ++d) {
    q4[d] = *(const f32x4*)(qp + d * 4);
    ca[d] = f32x4{0.f, 0.f, 0.f, 0.f};
  }
  const float* kb = lk + (size_t)batch * SEQ * 32;
  const float* vb = lv + (size_t)batch * SEQ * 32;
  float m = -INFINITY, ssum = 0.f;
  const float scale = 0.17677669529663687f;  // 1/sqrt(32)
  for (int j0 = 0; j0 <= qi; j0 += 64) {
    int j = j0 + lane;
    if (j <= qi) {
      const f32x4* kp = (const f32x4*)(kb + (size_t)j * 32);
      f32x4 s4 = f32x4{0.f, 0.f, 0.f, 0.f};
#pragma unroll
      for (int d = 0; d < 8; ++d) s4 += q4[d] * kp[d];
      float s = (s4.x + s4.y + s4.z + s4.w) * scale;
      float mn = fmaxf(m, s);
      float f = __expf(m - mn);
      float p = __expf(s - mn);
      ssum = ssum * f + p;
      const f32x4* vp = (const f32x4*)(vb + (size_t)j * 32);
#pragma unroll
      for (int d = 0; d < 8; ++d) ca[d] = ca[d] * f + p * vp[d];
      m = mn;
    }
  }
  float M = m;
#pragma unroll
  for (int off = 32; off > 0; off >>= 1) M = fmaxf(M, __shfl_xor(M, off, 64));
  float sc = (m == -INFINITY) ? 0.f : __expf(m - M);
  ssum *= sc;
#pragma unroll
  for (int off = 32; off > 0; off >>= 1) ssum += __shfl_xor(ssum, off, 64);
#pragma unroll
  for (int d = 0; d < 8; ++d) {
    ca[d] *= sc;
#pragma unroll
    for (int off = 32; off > 0; off >>= 1) {
      ca[d].x += __shfl_xor(ca[d].x, off, 64);
      ca[d].y += __shfl_xor(ca[d].y, off, 64);
      ca[d].z += __shfl_xor(ca[d].z, off, 64);
      ca[d].w += __shfl_xor(ca[d].w, off, 64);
    }
  }
  float inv = 1.f / ssum;
  float outv = 0.f;
#pragma unroll
  for (int d = 0; d < 32; ++d) {
    if (lane == d) outv = ca[d >> 2][d & 3];
  }
  if (lane < 32) ctx[(size_t)qg * 32 + lane] = outv * inv;
}

// -------- upscale + tile(ctx x16) + LayerNorm -> bf16 enc --------
__global__ __launch_bounds__(512) void k_upln(
    const float* __restrict__ ctx, const float* __restrict__ latx,
    const float* __restrict__ Wu, const float* __restrict__ bu,
    const float* __restrict__ gamma, const float* __restrict__ beta,
    unsigned short* __restrict__ encb) {
  int r = blockIdx.x;
  int c = threadIdx.x;  // 0..511
  float acc = bu[c] + ctx[(size_t)r * 32 + (c & 31)];
  const float* lx = latx + (size_t)r * 32;
#pragma unroll
  for (int k = 0; k < 32; ++k) acc += lx[k] * Wu[k * EMBED + c];
  int lane = threadIdx.x & 63, w = threadIdx.x >> 6;
  float s1 = acc, s2 = acc * acc;
#pragma unroll
  for (int off = 32; off > 0; off >>= 1) {
    s1 += __shfl_xor(s1, off, 64);
    s2 += __shfl_xor(s2, off, 64);
  }
  __shared__ float r1[8], r2[8];
  if (lane == 0) { r1[w] = s1; r2[w] = s2; }
  __syncthreads();
  float t1 = 0.f, t2 = 0.f;
#pragma unroll
  for (int i = 0; i < 8; ++i) { t1 += r1[i]; t2 += r2[i]; }
  float mu = t1 * (1.f / 512.f);
  float var = t2 * (1.f / 512.f) - mu * mu;
  float rstd = rsqrtf(var + 1e-5f);
  float o = (acc - mu) * rstd * gamma[c] + beta[c];
  encb[(size_t)r * EMBED + c] = f2bf(o);
}

// -------- transpose + cast Wf [512][32000] f32 -> WfT [32000][512] bf16 -----
__global__ __launch_bounds__(256) void k_transcast(
    const float* __restrict__ Wf, unsigned short* __restrict__ wfT) {
  __shared__ float tile[64][65];
  int n0 = blockIdx.x * 64;
  int k0 = blockIdx.y * 64;
  int t = threadIdx.x;
  int rr = t >> 4;         // 0..15
  int cq = (t & 15) << 2;  // 0..60
#pragma unroll
  for (int p = 0; p < 4; ++p) {
    int kr = p * 16 + rr;
    f32x4 v = *(const f32x4*)(Wf + (size_t)(k0 + kr) * VOCAB + n0 + cq);
    tile[kr][cq + 0] = v.x;
    tile[kr][cq + 1] = v.y;
    tile[kr][cq + 2] = v.z;
    tile[kr][cq + 3] = v.w;
  }
  __syncthreads();
#pragma unroll
  for (int p = 0; p < 4; ++p) {
    int nr = p * 16 + rr;
    ushort4 u;
    u.x = f2bf(tile[cq + 0][nr]);
    u.y = f2bf(tile[cq + 1][nr]);
    u.z = f2bf(tile[cq + 2][nr]);
    u.w = f2bf(tile[cq + 3][nr]);
    *(ushort4*)(wfT + (size_t)(n0 + nr) * EMBED + k0 + cq) = u;
  }
}

// ===================== final GEMM, 256x256 deep-pipelined =====================
// C[4096][32000] = encb @ WfT^T + bf.  8 waves (2M x 4N), per-wave 128x64 out.
// BK=32 K-tiles in a 4-deep LDS ring (4 x 32KB = 128KB). Counted vmcnt(12)
// (3 tiles in flight, never drained in main loop), raw s_barrier, setprio
// around MFMA bursts, XOR-swizzled LDS via pre-swizzled global source (G21).

__device__ __forceinline__ void mfma16x16x32(f32x4& d, s16x8 a, s16x8 b) {
  asm("v_mfma_f32_16x16x32_bf16 %0, %1, %2, %0" : "+v"(d) : "v"(a), "v"(b));
}

__device__ __forceinline__ void gload16(const void* g, void* l) {
  __builtin_amdgcn_global_load_lds(
      (const __attribute__((address_space(1))) void*)g,
      (__attribute__((address_space(3))) void*)l, 16, 0, 0);
}

// Stage one BK=32 K-tile (A 256x32 + B 256x32 bf16) into lds_buf.
// Linear LDS dest (global_load_lds requirement); source kbyte pre-swizzled
// with the same involution the reads use: unit ^= (row&3).
__device__ __forceinline__ void stage_tile(const char* Ab, const char* Bb,
                                           char* lds_buf, int koff, int tid) {
#pragma unroll
  for (int i = 0; i < 2; ++i) {
    int o = i * 8192 + tid * 16;
    int row = o >> 6;
    int u = (o >> 4) & 3;
    int kb = ((u ^ (row & 3)) << 4);
    gload16(Ab + (size_t)row * 1024 + koff + kb, lds_buf + o);
  }
#pragma unroll
  for (int i = 0; i < 2; ++i) {
    int o = i * 8192 + tid * 16;
    int row = o >> 6;
    int u = (o >> 4) & 3;
    int kb = ((u ^ (row & 3)) << 4);
    gload16(Bb + (size_t)row * 1024 + koff + kb, lds_buf + 16384 + o);
  }
}

__global__ __launch_bounds__(512, 2) void k_gemm(
    const unsigned short* __restrict__ A,   // [4096][512] bf16
    const unsigned short* __restrict__ Bt,  // [32000][512] bf16
    const float* __restrict__ bias, float* __restrict__ C) {
  __shared__ char lds[4 * 32768];
  int tid = threadIdx.x;
  int lane = tid & 63, wave = tid >> 6;
  int wm = wave >> 2, wn = wave & 3;  // 2 x 4 wave grid
  int fr = lane & 15, fq = lane >> 4;
  int kswz = (fq ^ (fr & 3)) << 4;  // read-side XOR swizzle (row&3 == fr&3)

  // XCD-bijective swizzle: 2000 blocks, 2000 % 8 == 0 -> chunk 250/XCD,
  // each XCD owns 2 consecutive bm rows (A panel L2-resident).
  int id = blockIdx.x;
  int nid = (id & 7) * 250 + (id >> 3);
  int bm = nid / 125, bn = nid - bm * 125;
  int m0 = bm * 256, n0 = bn * 256;

  const char* Ab = (const char*)(A + (size_t)m0 * EMBED);
  const char* Bb = (const char*)(Bt + (size_t)n0 * EMBED);

  f32x4 acc[8][4];
#pragma unroll
  for (int i = 0; i < 8; ++i)
#pragma unroll
    for (int j = 0; j < 4; ++j) acc[i][j] = f32x4{0.f, 0.f, 0.f, 0.f};

  // prologue: stage tiles 0,1,2 into ring slots 0,1,2
  stage_tile(Ab, Bb, lds + 0 * 32768, 0 * 64, tid);
  stage_tile(Ab, Bb, lds + 1 * 32768, 1 * 64, tid);
  stage_tile(Ab, Bb, lds + 2 * 32768, 2 * 64, tid);

  for (int t = 0; t < 16; ++t) {
    if (t <= 12) {
      stage_tile(Ab, Bb, lds + ((t + 3) & 3) * 32768, (t + 3) * 64, tid);
      asm volatile("s_waitcnt vmcnt(12)" ::: "memory");  // tile t landed
    } else if (t == 13) {
      asm volatile("s_waitcnt vmcnt(0)" ::: "memory");  // tail drain
    }
    __builtin_amdgcn_s_barrier();
    __builtin_amdgcn_sched_barrier(0);

    const char* Abuf = lds + (t & 3) * 32768;
    const char* Bbuf = Abuf + 16384;
    s16x8 bv4[4], av[8];
#pragma unroll
    for (int ni = 0; ni < 4; ++ni) {
      int row = wn * 64 + ni * 16 + fr;
      bv4[ni] = *(const s16x8*)(Bbuf + row * 64 + kswz);
    }
#pragma unroll
    for (int mi = 0; mi < 8; ++mi) {
      int row = wm * 128 + mi * 16 + fr;
      av[mi] = *(const s16x8*)(Abuf + row * 64 + kswz);
    }
    __builtin_amdgcn_s_setprio(1);
#pragma unroll
    for (int mi = 0; mi < 8; ++mi)
#pragma unroll
      for (int ni = 0; ni < 4; ++ni) mfma16x16x32(acc[mi][ni], av[mi], bv4[ni]);
    __builtin_amdgcn_s_setprio(0);
    __builtin_amdgcn_sched_barrier(0);
    __builtin_amdgcn_s_barrier();  // readers of slot t&3 done -> reusable
  }

  // epilogue: bias + f32 store. D layout: col=lane&15, row=(lane>>4)*4+reg
  float bvv[4];
#pragma unroll
  for (int ni = 0; ni < 4; ++ni) bvv[ni] = bias[n0 + wn * 64 + ni * 16 + fr];
#pragma unroll
  for (int mi = 0; mi < 8; ++mi) {
#pragma unroll
    for (int rg = 0; rg < 4; ++rg) {
      int rowg = m0 + wm * 128 + mi * 16 + fq * 4 + rg;
      float* crow = C + (size_t)rowg * VOCAB + n0 + wn * 64 + fr;
#pragma unroll
      for (int ni = 0; ni < 4; ++ni) crow[ni * 16] = acc[mi][ni][rg] + bvv[ni];
    }
  }
}

extern "C" void kernel_launch(void* const* d_in, const int* in_sizes, int n_in,
                              void* d_out, int out_size, void* d_ws,
                              size_t ws_size, hipStream_t stream) {
  (void)in_sizes; (void)n_in; (void)out_size; (void)ws_size;
  const float* Q = (const float*)d_in[0];
  const float* K = (const float*)d_in[1];
  const float* V = (const float*)d_in[2];
  const float* X = (const float*)d_in[3];
  const float* Wd = (const float*)d_in[4];
  const float* bd = (const float*)d_in[5];
  const float* Wu = (const float*)d_in[6];
  const float* bu = (const float*)d_in[7];
  const float* gamma = (const float*)d_in[8];
  const float* beta = (const float*)d_in[9];
  const float* Wf = (const float*)d_in[10];
  const float* bf = (const float*)d_in[11];
  float* out = (float*)d_out;
  char* ws = (char*)d_ws;
  float* latq = (float*)(ws + 0);
  float* latk = (float*)(ws + (1u << 19));
  float* latv = (float*)(ws + (2u << 19));
  float* latx = (float*)(ws + 3u * (1u << 19));
  float* ctx = (float*)(ws + (1u << 21));
  unsigned short* encb = (unsigned short*)(ws + (1u << 21) + (1u << 19));
  unsigned short* wfT =
      (unsigned short*)(ws + (1u << 21) + (1u << 19) + (1u << 22));

  k_downscale<<<dim3(MTOT, 4), 128, 0, stream>>>(Q, K, V, X, Wd, bd, latq,
                                                 latk, latv, latx);
  k_transcast<<<dim3(VOCAB / 64, EMBED / 64), 256, 0, stream>>>(Wf, wfT);
  k_attn<<<1024, 256, 0, stream>>>(latq, latk, latv, ctx);
  k_upln<<<MTOT, 512, 0, stream>>>(ctx, latx, Wu, bu, gamma, beta, encb);
  k_gemm<<<2000, 512, 0, stream>>>(encb, wfT, bf, out);
}

// Round 3
// 417.694 us; speedup vs baseline: 1.1412x; 1.0299x over previous
//
#include <hip/hip_runtime.h>

#define EMBED 512
#define LATENT 32
#define SEQ 2048
#define MTOT 4096
#define VOCAB 32000

typedef float f32x4 __attribute__((ext_vector_type(4)));
typedef short s16x8 __attribute__((ext_vector_type(8)));

__device__ __forceinline__ unsigned short f2bf(float f) {
  unsigned u = __float_as_uint(f);
  u += 0x7FFFu + ((u >> 16) & 1u);
  return (unsigned short)(u >> 16);
}

// ---------------- downscale: lat = in @ Wd + bd (4 streams) -----------------
__global__ __launch_bounds__(128) void k_downscale(
    const float* __restrict__ Q, const float* __restrict__ K,
    const float* __restrict__ V, const float* __restrict__ X,
    const float* __restrict__ Wd, const float* __restrict__ bd,
    float* __restrict__ latq, float* __restrict__ latk,
    float* __restrict__ latv, float* __restrict__ latx) {
  const float* in; float* out;
  switch (blockIdx.y) {
    case 0: in = Q; out = latq; break;
    case 1: in = K; out = latk; break;
    case 2: in = V; out = latv; break;
    default: in = X; out = latx; break;
  }
  int r = blockIdx.x;
  int t = threadIdx.x;
  int col = t & 31, part = t >> 5;
  const float* rowp = in + (size_t)r * EMBED + part * 128;
  const float* wd = Wd + col;
  float acc = 0.f;
#pragma unroll 8
  for (int kk = 0; kk < 128; kk += 4) {
    f32x4 iv = *(const f32x4*)(rowp + kk);
    int k = part * 128 + kk;
    acc += iv.x * wd[(k + 0) * 32];
    acc += iv.y * wd[(k + 1) * 32];
    acc += iv.z * wd[(k + 2) * 32];
    acc += iv.w * wd[(k + 3) * 32];
  }
  __shared__ float red[4][32];
  red[part][col] = acc;
  __syncthreads();
  if (t < 32) {
    out[(size_t)r * 32 + t] =
        red[0][t] + red[1][t] + red[2][t] + red[3][t] + bd[t];
  }
}

// ---------------- causal attention over latent dim 32 -----------------
__global__ __launch_bounds__(256) void k_attn(
    const float* __restrict__ lq, const float* __restrict__ lk,
    const float* __restrict__ lv, float* __restrict__ ctx) {
  int lane = threadIdx.x & 63;
  int lw = threadIdx.x >> 6;
  int bl = blockIdx.x;  // 0..1023
  int qg;
  switch (lw) {
    case 0: qg = bl; break;
    case 1: qg = 2047 - bl; break;
    case 2: qg = 2048 + bl; break;
    default: qg = 4095 - bl; break;
  }
  int batch = qg >> 11;
  int qi = qg & 2047;
  const float* qp = lq + (size_t)qg * 32;
  f32x4 q4[8], ca[8];
#pragma unroll
  for (int d = 0; d < 8; ++d) {
    q4[d] = *(const f32x4*)(qp + d * 4);
    ca[d] = f32x4{0.f, 0.f, 0.f, 0.f};
  }
  const float* kb = lk + (size_t)batch * SEQ * 32;
  const float* vb = lv + (size_t)batch * SEQ * 32;
  float m = -INFINITY, ssum = 0.f;
  const float scale = 0.17677669529663687f;  // 1/sqrt(32)
  for (int j0 = 0; j0 <= qi; j0 += 64) {
    int j = j0 + lane;
    if (j <= qi) {
      const f32x4* kp = (const f32x4*)(kb + (size_t)j * 32);
      f32x4 s4 = f32x4{0.f, 0.f, 0.f, 0.f};
#pragma unroll
      for (int d = 0; d < 8; ++d) s4 += q4[d] * kp[d];
      float s = (s4.x + s4.y + s4.z + s4.w) * scale;
      float mn = fmaxf(m, s);
      float f = __expf(m - mn);
      float p = __expf(s - mn);
      ssum = ssum * f + p;
      const f32x4* vp = (const f32x4*)(vb + (size_t)j * 32);
#pragma unroll
      for (int d = 0; d < 8; ++d) ca[d] = ca[d] * f + p * vp[d];
      m = mn;
    }
  }
  float M = m;
#pragma unroll
  for (int off = 32; off > 0; off >>= 1) M = fmaxf(M, __shfl_xor(M, off, 64));
  float sc = (m == -INFINITY) ? 0.f : __expf(m - M);
  ssum *= sc;
#pragma unroll
  for (int off = 32; off > 0; off >>= 1) ssum += __shfl_xor(ssum, off, 64);
#pragma unroll
  for (int d = 0; d < 8; ++d) {
    ca[d] *= sc;
#pragma unroll
    for (int off = 32; off > 0; off >>= 1) {
      ca[d].x += __shfl_xor(ca[d].x, off, 64);
      ca[d].y += __shfl_xor(ca[d].y, off, 64);
      ca[d].z += __shfl_xor(ca[d].z, off, 64);
      ca[d].w += __shfl_xor(ca[d].w, off, 64);
    }
  }
  float inv = 1.f / ssum;
  float outv = 0.f;
#pragma unroll
  for (int d = 0; d < 32; ++d) {
    if (lane == d) outv = ca[d >> 2][d & 3];
  }
  if (lane < 32) ctx[(size_t)qg * 32 + lane] = outv * inv;
}

// -------- upscale + tile(ctx x16) + LayerNorm -> bf16 enc --------
__global__ __launch_bounds__(512) void k_upln(
    const float* __restrict__ ctx, const float* __restrict__ latx,
    const float* __restrict__ Wu, const float* __restrict__ bu,
    const float* __restrict__ gamma, const float* __restrict__ beta,
    unsigned short* __restrict__ encb) {
  int r = blockIdx.x;
  int c = threadIdx.x;  // 0..511
  float acc = bu[c] + ctx[(size_t)r * 32 + (c & 31)];
  const float* lx = latx + (size_t)r * 32;
#pragma unroll
  for (int k = 0; k < 32; ++k) acc += lx[k] * Wu[k * EMBED + c];
  int lane = threadIdx.x & 63, w = threadIdx.x >> 6;
  float s1 = acc, s2 = acc * acc;
#pragma unroll
  for (int off = 32; off > 0; off >>= 1) {
    s1 += __shfl_xor(s1, off, 64);
    s2 += __shfl_xor(s2, off, 64);
  }
  __shared__ float r1[8], r2[8];
  if (lane == 0) { r1[w] = s1; r2[w] = s2; }
  __syncthreads();
  float t1 = 0.f, t2 = 0.f;
#pragma unroll
  for (int i = 0; i < 8; ++i) { t1 += r1[i]; t2 += r2[i]; }
  float mu = t1 * (1.f / 512.f);
  float var = t2 * (1.f / 512.f) - mu * mu;
  float rstd = rsqrtf(var + 1e-5f);
  float o = (acc - mu) * rstd * gamma[c] + beta[c];
  encb[(size_t)r * EMBED + c] = f2bf(o);
}

// -------- transpose + cast Wf [512][32000] f32 -> WfT [32000][512] bf16 -----
__global__ __launch_bounds__(256) void k_transcast(
    const float* __restrict__ Wf, unsigned short* __restrict__ wfT) {
  __shared__ float tile[64][65];
  int n0 = blockIdx.x * 64;
  int k0 = blockIdx.y * 64;
  int t = threadIdx.x;
  int rr = t >> 4;         // 0..15
  int cq = (t & 15) << 2;  // 0..60
#pragma unroll
  for (int p = 0; p < 4; ++p) {
    int kr = p * 16 + rr;
    f32x4 v = *(const f32x4*)(Wf + (size_t)(k0 + kr) * VOCAB + n0 + cq);
    tile[kr][cq + 0] = v.x;
    tile[kr][cq + 1] = v.y;
    tile[kr][cq + 2] = v.z;
    tile[kr][cq + 3] = v.w;
  }
  __syncthreads();
#pragma unroll
  for (int p = 0; p < 4; ++p) {
    int nr = p * 16 + rr;
    ushort4 u;
    u.x = f2bf(tile[cq + 0][nr]);
    u.y = f2bf(tile[cq + 1][nr]);
    u.z = f2bf(tile[cq + 2][nr]);
    u.w = f2bf(tile[cq + 3][nr]);
    *(ushort4*)(wfT + (size_t)(n0 + nr) * EMBED + k0 + cq) = u;
  }
}

// ============ final GEMM, 256x256, 8-phase-template schedule ============
// C[4096][32000] = encb @ WfT^T + bf. 8 waves (2M x 4N), per-wave 128x64.
// BK=32 K-tiles in a 4-slot LDS ring (128 KiB), ring distance 3, half-stages
// (2 gloads) issued one per phase. 2 phases per K-tile, 16 MFMA each, raw
// s_barrier pairs, counted vmcnt(8) once per tile (tail 4/0). Bank-quad
// swizzle for 64B rows: unit ^= (row>>1)&3 (8 lanes/quad = LDS BW limit),
// same involution pre-applied to the staging global source. NT stores keep
// the 512MB output stream out of L2; bn-major XCD swizzle keeps B hot in L2.

__device__ __forceinline__ void mfma16x16x32(f32x4& d, s16x8 a, s16x8 b) {
  asm("v_mfma_f32_16x16x32_bf16 %0, %1, %2, %0" : "+v"(d) : "v"(a), "v"(b));
}

__device__ __forceinline__ void gload16(const void* g, void* l) {
  __builtin_amdgcn_global_load_lds(
      (const __attribute__((address_space(1))) void*)g,
      (__attribute__((address_space(3))) void*)l, 16, 0, 0);
}

// Issue 2 global_load_lds covering one 256x32 bf16 half (A or B panel).
__device__ __forceinline__ void stage2(const char* base, char* slot, int koff,
                                       int tid) {
#pragma unroll
  for (int i = 0; i < 2; ++i) {
    int o = i * 8192 + tid * 16;
    int row = o >> 6;
    int u = (o >> 4) & 3;
    int kb = (u ^ ((row >> 1) & 3)) << 4;
    gload16(base + (size_t)row * 1024 + koff + kb, slot + o);
  }
}

__global__ __launch_bounds__(512, 2) void k_gemm(
    const unsigned short* __restrict__ A,   // [4096][512] bf16
    const unsigned short* __restrict__ Bt,  // [32000][512] bf16
    const float* __restrict__ bias, float* __restrict__ C) {
  __shared__ char lds[4][32768];
  int tid = threadIdx.x;
  int lane = tid & 63, wave = tid >> 6;
  int wm = wave >> 2, wn = wave & 3;  // 2 x 4 wave grid
  int fr = lane & 15, fq = lane >> 4;
  int kswz = (fq ^ ((fr >> 1) & 3)) << 4;  // (row>>1)&3 == (fr>>1)&3

  // bn-major XCD swizzle: 2000 blocks = 16 bm x 125 bn; each XCD gets 250
  // consecutive nids -> ~16 bn panels, all bm (A fully L2-hot, B ~0.5MB hot).
  int id = blockIdx.x;
  int nid = (id & 7) * 250 + (id >> 3);
  int bm = nid & 15, bn = nid >> 4;
  int m0 = bm * 256, n0 = bn * 256;

  const char* Ab = (const char*)(A + (size_t)m0 * EMBED);
  const char* Bb = (const char*)(Bt + (size_t)n0 * EMBED);

  f32x4 acc[8][4];
#pragma unroll
  for (int i = 0; i < 8; ++i)
#pragma unroll
    for (int j = 0; j < 4; ++j) acc[i][j] = f32x4{0.f, 0.f, 0.f, 0.f};

  // prologue: tiles 0,1,2 -> slots 0,1,2 (A then B halves each)
  stage2(Ab, &lds[0][0], 0, tid);
  stage2(Bb, &lds[0][16384], 0, tid);
  stage2(Ab, &lds[1][0], 64, tid);
  stage2(Bb, &lds[1][16384], 64, tid);
  stage2(Ab, &lds[2][0], 128, tid);
  stage2(Bb, &lds[2][16384], 128, tid);
  asm volatile("s_waitcnt vmcnt(8)" ::: "memory");  // tile 0 landed
  __builtin_amdgcn_s_barrier();

  for (int kt = 0; kt < 16; ++kt) {
    const char* Abuf = &lds[kt & 3][0];
    const char* Bbuf = Abuf + 16384;
    char* nslot = &lds[(kt + 3) & 3][0];
    int koff = (kt + 3) * 64;
    s16x8 bfrag[4], afrag[4];

    // ---------------- phase 0: B frags + A rows 0..63, MFMA upper half ----
#pragma unroll
    for (int ni = 0; ni < 4; ++ni) {
      int row = wn * 64 + ni * 16 + fr;
      bfrag[ni] = *(const s16x8*)(Bbuf + row * 64 + kswz);
    }
#pragma unroll
    for (int mi = 0; mi < 4; ++mi) {
      int row = wm * 128 + mi * 16 + fr;
      afrag[mi] = *(const s16x8*)(Abuf + row * 64 + kswz);
    }
    if (kt <= 12) stage2(Ab, nslot, koff, tid);
    __builtin_amdgcn_sched_barrier(0);
    __builtin_amdgcn_s_barrier();
    asm volatile("s_waitcnt lgkmcnt(0)" ::: "memory");
    __builtin_amdgcn_sched_barrier(0);
    __builtin_amdgcn_s_setprio(1);
#pragma unroll
    for (int mi = 0; mi < 4; ++mi)
#pragma unroll
      for (int ni = 0; ni < 4; ++ni) mfma16x16x32(acc[mi][ni], afrag[mi], bfrag[ni]);
    __builtin_amdgcn_s_setprio(0);
    __builtin_amdgcn_sched_barrier(0);
    __builtin_amdgcn_s_barrier();

    // ---------------- phase 1: A rows 64..127, MFMA lower half ------------
#pragma unroll
    for (int mi = 0; mi < 4; ++mi) {
      int row = wm * 128 + (mi + 4) * 16 + fr;
      afrag[mi] = *(const s16x8*)(Abuf + row * 64 + kswz);
    }
    if (kt <= 12) stage2(Bb, nslot + 16384, koff, tid);
    __builtin_amdgcn_sched_barrier(0);
    __builtin_amdgcn_s_barrier();
    asm volatile("s_waitcnt lgkmcnt(0)" ::: "memory");
    __builtin_amdgcn_sched_barrier(0);
    __builtin_amdgcn_s_setprio(1);
#pragma unroll
    for (int mi = 0; mi < 4; ++mi)
#pragma unroll
      for (int ni = 0; ni < 4; ++ni)
        mfma16x16x32(acc[mi + 4][ni], afrag[mi], bfrag[ni]);
    __builtin_amdgcn_s_setprio(0);
    __builtin_amdgcn_sched_barrier(0);
    // counted vmcnt once per tile: next tile's 4 loads (issued 2 tiles ago)
    if (kt <= 12) {
      asm volatile("s_waitcnt vmcnt(8)" ::: "memory");
    } else if (kt == 13) {
      asm volatile("s_waitcnt vmcnt(4)" ::: "memory");
    } else if (kt == 14) {
      asm volatile("s_waitcnt vmcnt(0)" ::: "memory");
    }
    __builtin_amdgcn_s_barrier();
  }

  // epilogue: bias + NT f32 store. D layout: col=lane&15, row=(lane>>4)*4+reg
  float bvv[4];
#pragma unroll
  for (int ni = 0; ni < 4; ++ni) bvv[ni] = bias[n0 + wn * 64 + ni * 16 + fr];
#pragma unroll
  for (int mi = 0; mi < 8; ++mi) {
#pragma unroll
    for (int rg = 0; rg < 4; ++rg) {
      int rowg = m0 + wm * 128 + mi * 16 + fq * 4 + rg;
      float* crow = C + (size_t)rowg * VOCAB + n0 + wn * 64 + fr;
#pragma unroll
      for (int ni = 0; ni < 4; ++ni)
        __builtin_nontemporal_store(acc[mi][ni][rg] + bvv[ni], &crow[ni * 16]);
    }
  }
}

extern "C" void kernel_launch(void* const* d_in, const int* in_sizes, int n_in,
                              void* d_out, int out_size, void* d_ws,
                              size_t ws_size, hipStream_t stream) {
  (void)in_sizes; (void)n_in; (void)out_size; (void)ws_size;
  const float* Q = (const float*)d_in[0];
  const float* K = (const float*)d_in[1];
  const float* V = (const float*)d_in[2];
  const float* X = (const float*)d_in[3];
  const float* Wd = (const float*)d_in[4];
  const float* bd = (const float*)d_in[5];
  const float* Wu = (const float*)d_in[6];
  const float* bu = (const float*)d_in[7];
  const float* gamma = (const float*)d_in[8];
  const float* beta = (const float*)d_in[9];
  const float* Wf = (const float*)d_in[10];
  const float* bf = (const float*)d_in[11];
  float* out = (float*)d_out;
  char* ws = (char*)d_ws;
  float* latq = (float*)(ws + 0);
  float* latk = (float*)(ws + (1u << 19));
  float* latv = (float*)(ws + (2u << 19));
  float* latx = (float*)(ws + 3u * (1u << 19));
  float* ctx = (float*)(ws + (1u << 21));
  unsigned short* encb = (unsigned short*)(ws + (1u << 21) + (1u << 19));
  unsigned short* wfT =
      (unsigned short*)(ws + (1u << 21) + (1u << 19) + (1u << 22));

  k_downscale<<<dim3(MTOT, 4), 128, 0, stream>>>(Q, K, V, X, Wd, bd, latq,
                                                 latk, latv, latx);
  k_transcast<<<dim3(VOCAB / 64, EMBED / 64), 256, 0, stream>>>(Wf, wfT);
  k_attn<<<1024, 256, 0, stream>>>(latq, latk, latv, ctx);
  k_upln<<<MTOT, 512, 0, stream>>>(ctx, latx, Wu, bu, gamma, beta, encb);
  k_gemm<<<2000, 512, 0, stream>>>(encb, wfT, bf, out);
}